// Round 6
// baseline (221.841 us; speedup 1.0000x reference)
//
#include <hip/hip_runtime.h>
#include <hip/hip_bf16.h>

#define S_LEN 4096
#define DMODEL 512
#define NHEAD 8
#define HDIM 64

typedef __bf16 bf16x8 __attribute__((ext_vector_type(8)));
typedef __bf16 bf16x4 __attribute__((ext_vector_type(4)));
typedef float f32x4 __attribute__((ext_vector_type(4)));

#define S2EXP 0.18033688011112042f   // 0.125 * log2(e)

__device__ __forceinline__ void gload_lds16(const void* g, void* l) {
    __builtin_amdgcn_global_load_lds((const __attribute__((address_space(1))) void*)g,
                                     (__attribute__((address_space(3))) void*)l, 16, 0, 0);
}

// ---------------- fused prologue ----------------
// bid <  512 : q+k projection (MFMA)
// bid < 1024 : v projection (MFMA) + transpose to vt[h][d][s]
// bid < 3072 : mask bit-packing
// bid < 3104 : Wfc f32->bf16
__global__ __launch_bounds__(256) void pre_kernel(const float* __restrict__ xq,
                                                  const float* __restrict__ xk,
                                                  const float* __restrict__ xv,
                                                  const float* __restrict__ Wq,
                                                  const float* __restrict__ bq,
                                                  const float* __restrict__ Wk,
                                                  const float* __restrict__ bk,
                                                  const float* __restrict__ Wv,
                                                  const float* __restrict__ bv,
                                                  __bf16* __restrict__ yq,
                                                  __bf16* __restrict__ yk,
                                                  __bf16* __restrict__ vt,
                                                  const int* __restrict__ mask,
                                                  unsigned int* __restrict__ pack,
                                                  const float* __restrict__ Wfc,
                                                  __bf16* __restrict__ wfc_bf) {
    __shared__ float T[64][65];
    int bid = blockIdx.x;
    int t = threadIdx.x, wave = t >> 6, lane = t & 63, lg = lane >> 4, lc = lane & 15;
    if (bid < 512) {
        int r0 = bid * 64 + wave * 16;
        const float* xrq = xq + (size_t)(r0 + lc) * 64 + lg * 8;
        const float* xrk = xk + (size_t)(r0 + lc) * 64 + lg * 8;
        bf16x8 aq[2], ak[2];
#pragma unroll
        for (int c = 0; c < 2; ++c) {
            f32x4 u0 = *(const f32x4*)(xrq + c * 32);
            f32x4 u1 = *(const f32x4*)(xrq + c * 32 + 4);
            f32x4 v0 = *(const f32x4*)(xrk + c * 32);
            f32x4 v1 = *(const f32x4*)(xrk + c * 32 + 4);
            bf16x8 a, b;
#pragma unroll
            for (int j = 0; j < 4; ++j) {
                a[j] = (__bf16)u0[j]; a[4 + j] = (__bf16)u1[j];
                b[j] = (__bf16)v0[j]; b[4 + j] = (__bf16)v1[j];
            }
            aq[c] = a; ak[c] = b;
        }
#pragma unroll
        for (int nt = 0; nt < 4; ++nt) {
            const float* wq = Wq + (size_t)(nt * 16 + lc) * 64 + lg * 8;
            const float* wk = Wk + (size_t)(nt * 16 + lc) * 64 + lg * 8;
            f32x4 cq = {0, 0, 0, 0}, ck = {0, 0, 0, 0};
#pragma unroll
            for (int c = 0; c < 2; ++c) {
                f32x4 u0 = *(const f32x4*)(wq + c * 32);
                f32x4 u1 = *(const f32x4*)(wq + c * 32 + 4);
                f32x4 v0 = *(const f32x4*)(wk + c * 32);
                f32x4 v1 = *(const f32x4*)(wk + c * 32 + 4);
                bf16x8 bw, bw2;
#pragma unroll
                for (int j = 0; j < 4; ++j) {
                    bw[j] = (__bf16)u0[j]; bw[4 + j] = (__bf16)u1[j];
                    bw2[j] = (__bf16)v0[j]; bw2[4 + j] = (__bf16)v1[j];
                }
                cq = __builtin_amdgcn_mfma_f32_16x16x32_bf16(aq[c], bw, cq, 0, 0, 0);
                ck = __builtin_amdgcn_mfma_f32_16x16x32_bf16(ak[c], bw2, ck, 0, 0, 0);
            }
            float bqv = bq[nt * 16 + lc], bkv = bk[nt * 16 + lc];
#pragma unroll
            for (int r = 0; r < 4; ++r) {
                yq[(size_t)(r0 + lg * 4 + r) * 64 + nt * 16 + lc] = (__bf16)(cq[r] + bqv);
                yk[(size_t)(r0 + lg * 4 + r) * 64 + nt * 16 + lc] = (__bf16)(ck[r] + bkv);
            }
        }
    } else if (bid < 1024) {
        int vb = bid - 512;
        int h = vb & 7, s0 = (vb >> 3) * 64;
        const float* xr = xv + ((size_t)(s0 + wave * 16 + lc) * 8 + h) * 64 + lg * 8;
        bf16x8 av[2];
#pragma unroll
        for (int c = 0; c < 2; ++c) {
            f32x4 u0 = *(const f32x4*)(xr + c * 32);
            f32x4 u1 = *(const f32x4*)(xr + c * 32 + 4);
            bf16x8 a;
#pragma unroll
            for (int j = 0; j < 4; ++j) { a[j] = (__bf16)u0[j]; a[4 + j] = (__bf16)u1[j]; }
            av[c] = a;
        }
#pragma unroll
        for (int nt = 0; nt < 4; ++nt) {
            const float* wv = Wv + (size_t)(nt * 16 + lc) * 64 + lg * 8;
            f32x4 cv = {0, 0, 0, 0};
#pragma unroll
            for (int c = 0; c < 2; ++c) {
                f32x4 u0 = *(const f32x4*)(wv + c * 32);
                f32x4 u1 = *(const f32x4*)(wv + c * 32 + 4);
                bf16x8 bw;
#pragma unroll
                for (int j = 0; j < 4; ++j) { bw[j] = (__bf16)u0[j]; bw[4 + j] = (__bf16)u1[j]; }
                cv = __builtin_amdgcn_mfma_f32_16x16x32_bf16(av[c], bw, cv, 0, 0, 0);
            }
            float bvv = bv[nt * 16 + lc];
#pragma unroll
            for (int r = 0; r < 4; ++r) T[wave * 16 + lg * 4 + r][nt * 16 + lc] = cv[r] + bvv;
        }
        __syncthreads();
        int d = t >> 2, qr = t & 3;
        bf16x8 w0, w1;
#pragma unroll
        for (int i = 0; i < 8; ++i) {
            w0[i] = (__bf16)T[qr * 16 + i][d];
            w1[i] = (__bf16)T[qr * 16 + 8 + i][d];
        }
        __bf16* dst = vt + ((size_t)h * 64 + d) * 4096 + s0 + qr * 16;
        *(bf16x8*)(dst) = w0;
        *(bf16x8*)(dst + 8) = w1;
    } else if (bid < 3072) {
        int wid = (bid - 1024) * 4 + (t >> 6);
#pragma unroll 4
        for (int it = 0; it < 32; ++it) {
            int gw = wid * 32 + it;
            int qi = gw >> 6, seg = gw & 63;
            unsigned long long bits = __ballot(mask[(size_t)qi * 4096 + seg * 64 + lane] != 0);
            if (lane == 0)
                *(unsigned long long*)(&pack[(size_t)qi * 128 + seg * 2]) = bits;
        }
    } else {
        int b = bid - 3072;
        const f32x4* s4 = (const f32x4*)Wfc;
#pragma unroll
        for (int i = 0; i < 8; ++i) {
            int idx = (b * 8 + i) * 256 + t;
            f32x4 v = s4[idx];
            bf16x4 o;
#pragma unroll
            for (int j = 0; j < 4; ++j) o[j] = (__bf16)v[j];
            *(bf16x4*)(wfc_bf + (size_t)idx * 4) = o;
        }
    }
}

// ---------------- flash attention: KV-step 32, 20KB LDS -> 8 blocks/CU ----------------
// block: h = bid&7 (head -> XCD), qt = (bid>>3)&63, sp = bid>>9
__global__ __launch_bounds__(256, 8) void attn_kernel(const __bf16* __restrict__ qb,
                                                      const __bf16* __restrict__ kb,
                                                      const __bf16* __restrict__ vt,
                                                      const unsigned int* __restrict__ mp,
                                                      int kv_len,
                                                      float* __restrict__ opart,
                                                      float* __restrict__ stats,
                                                      __bf16* __restrict__ ao) {
    int bid = blockIdx.x;
    int h = bid & 7, qt = (bid >> 3) & 63, sp = bid >> 9;
    int kv0 = sp * kv_len;
    int t = threadIdx.x, wave = t >> 6, lane = t & 63, lg = lane >> 4, lc = lane & 15;
    int q0 = qt * 64 + wave * 16;

    __shared__ __bf16 Kt[2][32 * 64];    // 4KB/buf: row k (128B), swz ((row&7)<<4)
    __shared__ __bf16 Vt[2][64 * 32];    // 4KB/buf: row d (64B),  swz ((row&3)<<4)
    __shared__ __bf16 P[4][16 * 32];     // 1KB/wave: row q (64B), swz ((row&3)<<4)

    // K staging geometry (8 rows x 128B per instr)
    int srK = lane >> 3;                             // row within 8
    int cgK = (lane & 7) ^ srK;                      // inverse-swizzled source chunk
    // V staging geometry (16 rows x 64B per instr)
    int srV = lane >> 2;                             // row within 16
    int cgV = (lane & 3) ^ (srV & 3);

    const __bf16* qrow = qb + ((size_t)(q0 + lc) * 8 + h) * 64 + lg * 8;
    bf16x8 qf0 = *(const bf16x8*)(qrow);
    bf16x8 qf1 = *(const bf16x8*)(qrow + 32);

    bf16x8 onesf;
#pragma unroll
    for (int j = 0; j < 8; ++j) onesf[j] = (__bf16)1.0f;

    f32x4 o0 = {0,0,0,0}, o1 = {0,0,0,0}, o2 = {0,0,0,0}, o3 = {0,0,0,0};
    f32x4 l_acc = {0,0,0,0};

    const unsigned int* mrow = mp + (size_t)(q0 + lc) * 128;
    const __bf16* vbase = vt + (size_t)h * 64 * 4096;

    // ---- stage tile 0: wave w stages K-instr w and V-instr w ----
    gload_lds16(kb + (size_t)(kv0 + wave * 8 + srK) * 512 + h * 64 + cgK * 8, &Kt[0][wave * 512]);
    gload_lds16(vbase + (size_t)(wave * 16 + srV) * 4096 + kv0 + cgV * 8,     &Vt[0][wave * 512]);
    __syncthreads();

    int nsteps = kv_len >> 5;
    for (int step = 0; step < nsteps; ++step) {
        int cur = step & 1;
        int kb_i = kv0 + step * 32;
        if (step < nsteps - 1) {
            int nxt = kb_i + 32;
            gload_lds16(kb + (size_t)(nxt + wave * 8 + srK) * 512 + h * 64 + cgK * 8, &Kt[cur ^ 1][wave * 512]);
            gload_lds16(vbase + (size_t)(wave * 16 + srV) * 4096 + nxt + cgV * 8,     &Vt[cur ^ 1][wave * 512]);
        }
        // ---- QK^T swapped: sc[kc][r] = score[k = kb_i+kc*16+lg*4+r][q = q0+lc] ----
        const char* Kb = (const char*)&Kt[cur][0];
        f32x4 sc[2];
#pragma unroll
        for (int kc = 0; kc < 2; ++kc) {
            int row = kc * 16 + lc;
            int sw = (row & 7) << 4;
            bf16x8 kf0 = *(const bf16x8*)(Kb + ((row * 128 + lg * 16) ^ sw));
            bf16x8 kf1 = *(const bf16x8*)(Kb + ((row * 128 + 64 + lg * 16) ^ sw));
            f32x4 z = {0,0,0,0};
            z = __builtin_amdgcn_mfma_f32_16x16x32_bf16(kf0, qf0, z, 0, 0, 0);
            z = __builtin_amdgcn_mfma_f32_16x16x32_bf16(kf1, qf1, z, 0, 0, 0);
            sc[kc] = z;
        }
        // ---- p = exp2(score*0.125*log2e), masked to 0 via sign-extended-bit AND ----
        unsigned int mw = mrow[kb_i >> 5];
        char* pbase = (char*)&P[wave][0];
        int psw = (lc & 3) << 4;
#pragma unroll
        for (int kc = 0; kc < 2; ++kc) {
            bf16x4 pk;
#pragma unroll
            for (int r = 0; r < 4; ++r) {
                int bitpos = kc * 16 + lg * 4 + r;
                float p = __builtin_amdgcn_exp2f(sc[kc][r] * S2EXP);
                int sel = ((int)(mw << (31 - bitpos))) >> 31;
                pk[r] = (__bf16)__int_as_float(__float_as_int(p) & sel);
            }
            int byte = (lc * 64 + kc * 32 + lg * 8) ^ psw;
            *(bf16x4*)(pbase + byte) = pk;
        }
        // ---- PV (+ l row-sum via ones-B MFMA): single K=32 chunk ----
        const char* Vb = (const char*)&Vt[cur][0];
        bf16x8 pf = *(const bf16x8*)(pbase + ((lc * 64 + lg * 16) ^ psw));
        l_acc = __builtin_amdgcn_mfma_f32_16x16x32_bf16(pf, onesf, l_acc, 0, 0, 0);
#pragma unroll
        for (int dt = 0; dt < 4; ++dt) {
            int row = dt * 16 + lc;
            bf16x8 vf = *(const bf16x8*)(Vb + ((row * 64 + lg * 16) ^ ((row & 3) << 4)));
            if (dt == 0) o0 = __builtin_amdgcn_mfma_f32_16x16x32_bf16(pf, vf, o0, 0, 0, 0);
            if (dt == 1) o1 = __builtin_amdgcn_mfma_f32_16x16x32_bf16(pf, vf, o1, 0, 0, 0);
            if (dt == 2) o2 = __builtin_amdgcn_mfma_f32_16x16x32_bf16(pf, vf, o2, 0, 0, 0);
            if (dt == 3) o3 = __builtin_amdgcn_mfma_f32_16x16x32_bf16(pf, vf, o3, 0, 0, 0);
        }
        __syncthreads();
    }
    if (opart) {
        if (lc == 0) {
#pragma unroll
            for (int r = 0; r < 4; ++r)
                stats[(size_t)sp * 32768 + (size_t)(q0 + lg * 4 + r) * 8 + h] = l_acc[r];
        }
#pragma unroll
        for (int r = 0; r < 4; ++r) {
            size_t rh = (size_t)sp * 32768 + (size_t)(q0 + lg * 4 + r) * 8 + h;
            float* dst = opart + rh * 64;
            dst[0 * 16 + lc] = o0[r];
            dst[1 * 16 + lc] = o1[r];
            dst[2 * 16 + lc] = o2[r];
            dst[3 * 16 + lc] = o3[r];
        }
    } else {
#pragma unroll
        for (int r = 0; r < 4; ++r) {
            float inv = 1.0f / l_acc[r];
            int row = q0 + lg * 4 + r;
            __bf16* dst = ao + (size_t)row * 512 + h * 64;
            dst[0 * 16 + lc] = (__bf16)(o0[r] * inv);
            dst[1 * 16 + lc] = (__bf16)(o1[r] * inv);
            dst[2 * 16 + lc] = (__bf16)(o2[r] * inv);
            dst[3 * 16 + lc] = (__bf16)(o3[r] * inv);
        }
    }
}

// ---------------- split-KV combine (no-max softmax: plain sums) ----------------
__global__ __launch_bounds__(256) void combine_kernel(const float* __restrict__ opart,
                                                      const float* __restrict__ stats,
                                                      __bf16* __restrict__ ao, int nsplit) {
    int t = threadIdx.x, lane = t & 63, w = t >> 6;
    int rh = blockIdx.x * 4 + w;     // row*8 + h
    float L = 0.f, acc = 0.f;
#pragma unroll 4
    for (int sp = 0; sp < nsplit; ++sp) {
        L += stats[(size_t)sp * 32768 + rh];
        acc += opart[((size_t)sp * 32768 + rh) * 64 + lane];
    }
    int row = rh >> 3, h = rh & 7;
    ao[(size_t)row * 512 + h * 64 + lane] = (__bf16)(acc / L);
}

// ---------------- final FC: out[s][n] = sum_k ao[s][k] * Wfc[n][k] + bfc[n] ----------------
__global__ __launch_bounds__(256) void fc_kernel(const __bf16* __restrict__ ao,
                                                 const __bf16* __restrict__ Wb,
                                                 const float* __restrict__ bfc,
                                                 float* __restrict__ out) {
    int bid = blockIdx.x;
    int stile = bid >> 3, nt = bid & 7;
    int t = threadIdx.x, wave = t >> 6, lane = t & 63, lg = lane >> 4, lc = lane & 15;
    int s0 = stile * 64 + wave * 16;
    int n0 = nt * 64;
    f32x4 c0 = {0,0,0,0}, c1 = {0,0,0,0}, c2 = {0,0,0,0}, c3 = {0,0,0,0};
    for (int k0 = 0; k0 < 512; k0 += 32) {
        bf16x8 af = *(const bf16x8*)(ao + (size_t)(s0 + lc) * 512 + k0 + lg * 8);
        const __bf16* wb = Wb + k0 + lg * 8;
        c0 = __builtin_amdgcn_mfma_f32_16x16x32_bf16(af, *(const bf16x8*)(wb + (size_t)(n0 + 0 * 16 + lc) * 512), c0, 0, 0, 0);
        c1 = __builtin_amdgcn_mfma_f32_16x16x32_bf16(af, *(const bf16x8*)(wb + (size_t)(n0 + 1 * 16 + lc) * 512), c1, 0, 0, 0);
        c2 = __builtin_amdgcn_mfma_f32_16x16x32_bf16(af, *(const bf16x8*)(wb + (size_t)(n0 + 2 * 16 + lc) * 512), c2, 0, 0, 0);
        c3 = __builtin_amdgcn_mfma_f32_16x16x32_bf16(af, *(const bf16x8*)(wb + (size_t)(n0 + 3 * 16 + lc) * 512), c3, 0, 0, 0);
    }
#pragma unroll
    for (int r = 0; r < 4; ++r) {
        int row = s0 + lg * 4 + r;
        float* dst = out + (size_t)row * 512 + n0;
        dst[0 * 16 + lc] = c0[r] + bfc[n0 + 0 * 16 + lc];
        dst[1 * 16 + lc] = c1[r] + bfc[n0 + 1 * 16 + lc];
        dst[2 * 16 + lc] = c2[r] + bfc[n0 + 2 * 16 + lc];
        dst[3 * 16 + lc] = c3[r] + bfc[n0 + 3 * 16 + lc];
    }
}

extern "C" void kernel_launch(void* const* d_in, const int* in_sizes, int n_in,
                              void* d_out, int out_size, void* d_ws, size_t ws_size,
                              hipStream_t stream) {
    const float* query = (const float*)d_in[0];
    const float* key   = (const float*)d_in[1];
    const float* value = (const float*)d_in[2];
    const int*   mask  = (const int*)d_in[3];
    const float* Wq  = (const float*)d_in[4];
    const float* bq  = (const float*)d_in[5];
    const float* Wk  = (const float*)d_in[6];
    const float* bk  = (const float*)d_in[7];
    const float* Wv  = (const float*)d_in[8];
    const float* bv  = (const float*)d_in[9];
    const float* Wfc = (const float*)d_in[10];
    const float* bfc = (const float*)d_in[11];

    char* ws = (char*)d_ws;
    const size_t MB = 1024 * 1024;
    __bf16* q_bf   = (__bf16*)(ws + 0 * MB);      // 4 MB  [S*H][64]
    __bf16* k_bf   = (__bf16*)(ws + 4 * MB);      // 4 MB  [S*H][64]
    __bf16* vt     = (__bf16*)(ws + 8 * MB);      // 4 MB  [H][64][S]
    __bf16* ao     = (__bf16*)(ws + 12 * MB);     // 4 MB  [S][512]
    __bf16* wfc_bf = (__bf16*)(ws + 16 * MB);     // 0.5 MB
    unsigned int* mpack = (unsigned int*)(ws + 17 * MB);  // 2 MB [S][128]
    const size_t base = 19 * MB;
    int nsplit = 1;
    if (ws_size >= base + 4 * (8 * MB) + 4 * 131072) nsplit = 4;
    else if (ws_size >= base + 2 * (8 * MB) + 2 * 131072) nsplit = 2;
    float* opart = (float*)(ws + base);
    float* stats = (float*)(ws + base + (size_t)nsplit * 8 * MB);

    pre_kernel<<<3104, 256, 0, stream>>>(query, key, value, Wq, bq, Wk, bk, Wv, bv,
                                         q_bf, k_bf, vt, mask, mpack, Wfc, wfc_bf);
    if (nsplit > 1) {
        attn_kernel<<<512 * nsplit, 256, 0, stream>>>(q_bf, k_bf, vt, mpack,
                                                      S_LEN / nsplit, opart, stats, ao);
        combine_kernel<<<8192, 256, 0, stream>>>(opart, stats, ao, nsplit);
    } else {
        attn_kernel<<<512, 256, 0, stream>>>(q_bf, k_bf, vt, mpack,
                                             S_LEN, nullptr, nullptr, ao);
    }
    fc_kernel<<<512, 256, 0, stream>>>(ao, wfc_bf, bfc, (float*)d_out);
}

// Round 7
// 138.280 us; speedup vs baseline: 1.6043x; 1.6043x over previous
//
#include <hip/hip_runtime.h>
#include <hip/hip_bf16.h>

#define S_LEN 4096
#define DMODEL 512
#define NHEAD 8
#define HDIM 64

typedef __bf16 bf16x8 __attribute__((ext_vector_type(8)));
typedef __bf16 bf16x4 __attribute__((ext_vector_type(4)));
typedef float f32x4 __attribute__((ext_vector_type(4)));

#define S2EXP 0.18033688011112042f   // 0.125 * log2(e)

__device__ __forceinline__ void gload_lds16(const void* g, void* l) {
    __builtin_amdgcn_global_load_lds((const __attribute__((address_space(1))) void*)g,
                                     (__attribute__((address_space(3))) void*)l, 16, 0, 0);
}

// ---------------- fused prologue ----------------
// bid <  512 : q+k projection (MFMA)
// bid < 1024 : v projection (MFMA) + transpose to vt[h][d][s]
// bid < 3072 : mask bit-packing
// bid < 3104 : Wfc f32->bf16
__global__ __launch_bounds__(256) void pre_kernel(const float* __restrict__ xq,
                                                  const float* __restrict__ xk,
                                                  const float* __restrict__ xv,
                                                  const float* __restrict__ Wq,
                                                  const float* __restrict__ bq,
                                                  const float* __restrict__ Wk,
                                                  const float* __restrict__ bk,
                                                  const float* __restrict__ Wv,
                                                  const float* __restrict__ bv,
                                                  __bf16* __restrict__ yq,
                                                  __bf16* __restrict__ yk,
                                                  __bf16* __restrict__ vt,
                                                  const int* __restrict__ mask,
                                                  unsigned int* __restrict__ pack,
                                                  const float* __restrict__ Wfc,
                                                  __bf16* __restrict__ wfc_bf) {
    __shared__ float T[64][65];
    int bid = blockIdx.x;
    int t = threadIdx.x, wave = t >> 6, lane = t & 63, lg = lane >> 4, lc = lane & 15;
    if (bid < 512) {
        int r0 = bid * 64 + wave * 16;
        const float* xrq = xq + (size_t)(r0 + lc) * 64 + lg * 8;
        const float* xrk = xk + (size_t)(r0 + lc) * 64 + lg * 8;
        bf16x8 aq[2], ak[2];
#pragma unroll
        for (int c = 0; c < 2; ++c) {
            f32x4 u0 = *(const f32x4*)(xrq + c * 32);
            f32x4 u1 = *(const f32x4*)(xrq + c * 32 + 4);
            f32x4 v0 = *(const f32x4*)(xrk + c * 32);
            f32x4 v1 = *(const f32x4*)(xrk + c * 32 + 4);
            bf16x8 a, b;
#pragma unroll
            for (int j = 0; j < 4; ++j) {
                a[j] = (__bf16)u0[j]; a[4 + j] = (__bf16)u1[j];
                b[j] = (__bf16)v0[j]; b[4 + j] = (__bf16)v1[j];
            }
            aq[c] = a; ak[c] = b;
        }
#pragma unroll
        for (int nt = 0; nt < 4; ++nt) {
            const float* wq = Wq + (size_t)(nt * 16 + lc) * 64 + lg * 8;
            const float* wk = Wk + (size_t)(nt * 16 + lc) * 64 + lg * 8;
            f32x4 cq = {0, 0, 0, 0}, ck = {0, 0, 0, 0};
#pragma unroll
            for (int c = 0; c < 2; ++c) {
                f32x4 u0 = *(const f32x4*)(wq + c * 32);
                f32x4 u1 = *(const f32x4*)(wq + c * 32 + 4);
                f32x4 v0 = *(const f32x4*)(wk + c * 32);
                f32x4 v1 = *(const f32x4*)(wk + c * 32 + 4);
                bf16x8 bw, bw2;
#pragma unroll
                for (int j = 0; j < 4; ++j) {
                    bw[j] = (__bf16)u0[j]; bw[4 + j] = (__bf16)u1[j];
                    bw2[j] = (__bf16)v0[j]; bw2[4 + j] = (__bf16)v1[j];
                }
                cq = __builtin_amdgcn_mfma_f32_16x16x32_bf16(aq[c], bw, cq, 0, 0, 0);
                ck = __builtin_amdgcn_mfma_f32_16x16x32_bf16(ak[c], bw2, ck, 0, 0, 0);
            }
            float bqv = bq[nt * 16 + lc], bkv = bk[nt * 16 + lc];
#pragma unroll
            for (int r = 0; r < 4; ++r) {
                yq[(size_t)(r0 + lg * 4 + r) * 64 + nt * 16 + lc] = (__bf16)(cq[r] + bqv);
                yk[(size_t)(r0 + lg * 4 + r) * 64 + nt * 16 + lc] = (__bf16)(ck[r] + bkv);
            }
        }
    } else if (bid < 1024) {
        int vb = bid - 512;
        int h = vb & 7, s0 = (vb >> 3) * 64;
        const float* xr = xv + ((size_t)(s0 + wave * 16 + lc) * 8 + h) * 64 + lg * 8;
        bf16x8 av[2];
#pragma unroll
        for (int c = 0; c < 2; ++c) {
            f32x4 u0 = *(const f32x4*)(xr + c * 32);
            f32x4 u1 = *(const f32x4*)(xr + c * 32 + 4);
            bf16x8 a;
#pragma unroll
            for (int j = 0; j < 4; ++j) { a[j] = (__bf16)u0[j]; a[4 + j] = (__bf16)u1[j]; }
            av[c] = a;
        }
#pragma unroll
        for (int nt = 0; nt < 4; ++nt) {
            const float* wv = Wv + (size_t)(nt * 16 + lc) * 64 + lg * 8;
            f32x4 cv = {0, 0, 0, 0};
#pragma unroll
            for (int c = 0; c < 2; ++c) {
                f32x4 u0 = *(const f32x4*)(wv + c * 32);
                f32x4 u1 = *(const f32x4*)(wv + c * 32 + 4);
                bf16x8 bw;
#pragma unroll
                for (int j = 0; j < 4; ++j) { bw[j] = (__bf16)u0[j]; bw[4 + j] = (__bf16)u1[j]; }
                cv = __builtin_amdgcn_mfma_f32_16x16x32_bf16(av[c], bw, cv, 0, 0, 0);
            }
            float bvv = bv[nt * 16 + lc];
#pragma unroll
            for (int r = 0; r < 4; ++r) T[wave * 16 + lg * 4 + r][nt * 16 + lc] = cv[r] + bvv;
        }
        __syncthreads();
        int d = t >> 2, qr = t & 3;
        bf16x8 w0, w1;
#pragma unroll
        for (int i = 0; i < 8; ++i) {
            w0[i] = (__bf16)T[qr * 16 + i][d];
            w1[i] = (__bf16)T[qr * 16 + 8 + i][d];
        }
        __bf16* dst = vt + ((size_t)h * 64 + d) * 4096 + s0 + qr * 16;
        *(bf16x8*)(dst) = w0;
        *(bf16x8*)(dst + 8) = w1;
    } else if (bid < 3072) {
        int wid = (bid - 1024) * 4 + (t >> 6);
#pragma unroll 4
        for (int it = 0; it < 32; ++it) {
            int gw = wid * 32 + it;
            int qi = gw >> 6, seg = gw & 63;
            unsigned long long bits = __ballot(mask[(size_t)qi * 4096 + seg * 64 + lane] != 0);
            if (lane == 0)
                *(unsigned long long*)(&pack[(size_t)qi * 128 + seg * 2]) = bits;
        }
    } else {
        int b = bid - 3072;
        const f32x4* s4 = (const f32x4*)Wfc;
#pragma unroll
        for (int i = 0; i < 8; ++i) {
            int idx = (b * 8 + i) * 256 + t;
            f32x4 v = s4[idx];
            bf16x4 o;
#pragma unroll
            for (int j = 0; j < 4; ++j) o[j] = (__bf16)v[j];
            *(bf16x4*)(wfc_bf + (size_t)idx * 4) = o;
        }
    }
}

// ---------------- flash attention: KV-step 32, 20KB LDS, 6 blocks/CU (no spills) ----------------
// block: h = bid&7 (head -> XCD), qt = (bid>>3)&63, sp = bid>>9
// split sp covers steps [sp*split_steps, min((sp+1)*split_steps, 128)) of 32 KV each
__global__ __launch_bounds__(256, 6) void attn_kernel(const __bf16* __restrict__ qb,
                                                      const __bf16* __restrict__ kb,
                                                      const __bf16* __restrict__ vt,
                                                      const unsigned int* __restrict__ mp,
                                                      int split_steps,
                                                      float* __restrict__ opart,
                                                      float* __restrict__ stats,
                                                      __bf16* __restrict__ ao) {
    int bid = blockIdx.x;
    int h = bid & 7, qt = (bid >> 3) & 63, sp = bid >> 9;
    int kv0 = sp * split_steps * 32;
    int nsteps = min(split_steps, 128 - sp * split_steps);
    int t = threadIdx.x, wave = t >> 6, lane = t & 63, lg = lane >> 4, lc = lane & 15;
    int q0 = qt * 64 + wave * 16;

    __shared__ __bf16 Kt[2][32 * 64];    // 4KB/buf: k-rows, 128B, XOR swz ((row&7)<<4)
    __shared__ __bf16 Vt[2][64 * 32];    // 4KB/buf: d-rows, 64B, chunk-rotation swz
    __shared__ __bf16 P[4][16 * 32];     // 1KB/wave: q-rows, 64B, chunk-rotation swz

    // K staging (8 rows x 128B per instr): phys chunk = lane&7, row srK
    int srK = lane >> 3;
    int cgK = (lane & 7) ^ srK;                      // inverse XOR swizzle
    // V staging (16 rows x 64B per instr): phys chunk = lane&3, row srV = lane>>2
    // rotation: phys = (logical + (row>>1)) & 3  ->  logical = (phys - (row>>1)) & 3
    int srV = lane >> 2;
    int cgV = ((lane & 3) - ((lane >> 3) & 3)) & 3;

    const __bf16* qrow = qb + ((size_t)(q0 + lc) * 8 + h) * 64 + lg * 8;
    bf16x8 qf0 = *(const bf16x8*)(qrow);
    bf16x8 qf1 = *(const bf16x8*)(qrow + 32);

    bf16x8 onesf;
#pragma unroll
    for (int j = 0; j < 8; ++j) onesf[j] = (__bf16)1.0f;

    f32x4 o0 = {0,0,0,0}, o1 = {0,0,0,0}, o2 = {0,0,0,0}, o3 = {0,0,0,0};
    f32x4 l_acc = {0,0,0,0};

    const unsigned int* mrow = mp + (size_t)(q0 + lc) * 128;
    const __bf16* vbase = vt + (size_t)h * 64 * 4096;

    // ---- stage tile 0: wave w stages K-instr w and V-instr w ----
    gload_lds16(kb + (size_t)(kv0 + wave * 8 + srK) * 512 + h * 64 + cgK * 8, &Kt[0][wave * 512]);
    gload_lds16(vbase + (size_t)(wave * 16 + srV) * 4096 + kv0 + cgV * 8,     &Vt[0][wave * 512]);
    __syncthreads();

    int rotP = (lc >> 1) & 3;            // rotation for P/V rows (row = lc mod 16)
    for (int step = 0; step < nsteps; ++step) {
        int cur = step & 1;
        int kb_i = kv0 + step * 32;
        if (step < nsteps - 1) {
            int nxt = kb_i + 32;
            gload_lds16(kb + (size_t)(nxt + wave * 8 + srK) * 512 + h * 64 + cgK * 8, &Kt[cur ^ 1][wave * 512]);
            gload_lds16(vbase + (size_t)(wave * 16 + srV) * 4096 + nxt + cgV * 8,     &Vt[cur ^ 1][wave * 512]);
        }
        // ---- QK^T swapped: sc[kc][r] = score[k = kb_i+kc*16+lg*4+r][q = q0+lc] ----
        const char* Kb = (const char*)&Kt[cur][0];
        f32x4 sc[2];
#pragma unroll
        for (int kc = 0; kc < 2; ++kc) {
            int row = kc * 16 + lc;
            int sw = (row & 7) << 4;
            bf16x8 kf0 = *(const bf16x8*)(Kb + ((row * 128 + lg * 16) ^ sw));
            bf16x8 kf1 = *(const bf16x8*)(Kb + ((row * 128 + 64 + lg * 16) ^ sw));
            f32x4 z = {0,0,0,0};
            z = __builtin_amdgcn_mfma_f32_16x16x32_bf16(kf0, qf0, z, 0, 0, 0);
            z = __builtin_amdgcn_mfma_f32_16x16x32_bf16(kf1, qf1, z, 0, 0, 0);
            sc[kc] = z;
        }
        // ---- p = exp2(score*0.125*log2e), masked to 0 via sign-extended-bit AND ----
        unsigned int mw = mrow[kb_i >> 5];
        char* pbase = (char*)&P[wave][0];
#pragma unroll
        for (int kc = 0; kc < 2; ++kc) {
            bf16x4 pk;
#pragma unroll
            for (int r = 0; r < 4; ++r) {
                int bitpos = kc * 16 + lg * 4 + r;
                float p = __builtin_amdgcn_exp2f(sc[kc][r] * S2EXP);
                int sel = ((int)(mw << (31 - bitpos))) >> 31;
                pk[r] = (__bf16)__int_as_float(__float_as_int(p) & sel);
            }
            // logical 16B chunk = kc*2 + (lg>>1); in-chunk 8B offset = (lg&1)*8
            int phys = ((kc * 2 + (lg >> 1)) + rotP) & 3;
            int byte = lc * 64 + phys * 16 + (lg & 1) * 8;
            *(bf16x4*)(pbase + byte) = pk;
        }
        // ---- PV (+ l row-sum via ones-B MFMA): single K=32 chunk ----
        const char* Vb = (const char*)&Vt[cur][0];
        bf16x8 pf = *(const bf16x8*)(pbase + (lc * 64 + (((lg + rotP) & 3) * 16)));
        l_acc = __builtin_amdgcn_mfma_f32_16x16x32_bf16(pf, onesf, l_acc, 0, 0, 0);
#pragma unroll
        for (int dt = 0; dt < 4; ++dt) {
            int row = dt * 16 + lc;
            bf16x8 vf = *(const bf16x8*)(Vb + (row * 64 + (((lg + rotP) & 3) * 16)));
            if (dt == 0) o0 = __builtin_amdgcn_mfma_f32_16x16x32_bf16(pf, vf, o0, 0, 0, 0);
            if (dt == 1) o1 = __builtin_amdgcn_mfma_f32_16x16x32_bf16(pf, vf, o1, 0, 0, 0);
            if (dt == 2) o2 = __builtin_amdgcn_mfma_f32_16x16x32_bf16(pf, vf, o2, 0, 0, 0);
            if (dt == 3) o3 = __builtin_amdgcn_mfma_f32_16x16x32_bf16(pf, vf, o3, 0, 0, 0);
        }
        __syncthreads();
    }
    if (opart) {
        if (lc == 0) {
#pragma unroll
            for (int r = 0; r < 4; ++r)
                stats[(size_t)sp * 32768 + (size_t)(q0 + lg * 4 + r) * 8 + h] = l_acc[r];
        }
#pragma unroll
        for (int r = 0; r < 4; ++r) {
            size_t rh = (size_t)sp * 32768 + (size_t)(q0 + lg * 4 + r) * 8 + h;
            float* dst = opart + rh * 64;
            dst[0 * 16 + lc] = o0[r];
            dst[1 * 16 + lc] = o1[r];
            dst[2 * 16 + lc] = o2[r];
            dst[3 * 16 + lc] = o3[r];
        }
    } else {
#pragma unroll
        for (int r = 0; r < 4; ++r) {
            float inv = 1.0f / l_acc[r];
            int row = q0 + lg * 4 + r;
            __bf16* dst = ao + (size_t)row * 512 + h * 64;
            dst[0 * 16 + lc] = (__bf16)(o0[r] * inv);
            dst[1 * 16 + lc] = (__bf16)(o1[r] * inv);
            dst[2 * 16 + lc] = (__bf16)(o2[r] * inv);
            dst[3 * 16 + lc] = (__bf16)(o3[r] * inv);
        }
    }
}

// ---------------- split-KV combine (no-max softmax: plain sums) ----------------
__global__ __launch_bounds__(256) void combine_kernel(const float* __restrict__ opart,
                                                      const float* __restrict__ stats,
                                                      __bf16* __restrict__ ao, int nsplit) {
    int t = threadIdx.x, lane = t & 63, w = t >> 6;
    int rh = blockIdx.x * 4 + w;     // row*8 + h
    float L = 0.f, acc = 0.f;
#pragma unroll 4
    for (int sp = 0; sp < nsplit; ++sp) {
        L += stats[(size_t)sp * 32768 + rh];
        acc += opart[((size_t)sp * 32768 + rh) * 64 + lane];
    }
    int row = rh >> 3, h = rh & 7;
    ao[(size_t)row * 512 + h * 64 + lane] = (__bf16)(acc / L);
}

// ---------------- final FC: out[s][n] = sum_k ao[s][k] * Wfc[n][k] + bfc[n] ----------------
__global__ __launch_bounds__(256) void fc_kernel(const __bf16* __restrict__ ao,
                                                 const __bf16* __restrict__ Wb,
                                                 const float* __restrict__ bfc,
                                                 float* __restrict__ out) {
    int bid = blockIdx.x;
    int stile = bid >> 3, nt = bid & 7;
    int t = threadIdx.x, wave = t >> 6, lane = t & 63, lg = lane >> 4, lc = lane & 15;
    int s0 = stile * 64 + wave * 16;
    int n0 = nt * 64;
    f32x4 c0 = {0,0,0,0}, c1 = {0,0,0,0}, c2 = {0,0,0,0}, c3 = {0,0,0,0};
    for (int k0 = 0; k0 < 512; k0 += 32) {
        bf16x8 af = *(const bf16x8*)(ao + (size_t)(s0 + lc) * 512 + k0 + lg * 8);
        const __bf16* wb = Wb + k0 + lg * 8;
        c0 = __builtin_amdgcn_mfma_f32_16x16x32_bf16(af, *(const bf16x8*)(wb + (size_t)(n0 + 0 * 16 + lc) * 512), c0, 0, 0, 0);
        c1 = __builtin_amdgcn_mfma_f32_16x16x32_bf16(af, *(const bf16x8*)(wb + (size_t)(n0 + 1 * 16 + lc) * 512), c1, 0, 0, 0);
        c2 = __builtin_amdgcn_mfma_f32_16x16x32_bf16(af, *(const bf16x8*)(wb + (size_t)(n0 + 2 * 16 + lc) * 512), c2, 0, 0, 0);
        c3 = __builtin_amdgcn_mfma_f32_16x16x32_bf16(af, *(const bf16x8*)(wb + (size_t)(n0 + 3 * 16 + lc) * 512), c3, 0, 0, 0);
    }
#pragma unroll
    for (int r = 0; r < 4; ++r) {
        int row = s0 + lg * 4 + r;
        float* dst = out + (size_t)row * 512 + n0;
        dst[0 * 16 + lc] = c0[r] + bfc[n0 + 0 * 16 + lc];
        dst[1 * 16 + lc] = c1[r] + bfc[n0 + 1 * 16 + lc];
        dst[2 * 16 + lc] = c2[r] + bfc[n0 + 2 * 16 + lc];
        dst[3 * 16 + lc] = c3[r] + bfc[n0 + 3 * 16 + lc];
    }
}

extern "C" void kernel_launch(void* const* d_in, const int* in_sizes, int n_in,
                              void* d_out, int out_size, void* d_ws, size_t ws_size,
                              hipStream_t stream) {
    const float* query = (const float*)d_in[0];
    const float* key   = (const float*)d_in[1];
    const float* value = (const float*)d_in[2];
    const int*   mask  = (const int*)d_in[3];
    const float* Wq  = (const float*)d_in[4];
    const float* bq  = (const float*)d_in[5];
    const float* Wk  = (const float*)d_in[6];
    const float* bk  = (const float*)d_in[7];
    const float* Wv  = (const float*)d_in[8];
    const float* bv  = (const float*)d_in[9];
    const float* Wfc = (const float*)d_in[10];
    const float* bfc = (const float*)d_in[11];

    char* ws = (char*)d_ws;
    const size_t MB = 1024 * 1024;
    __bf16* q_bf   = (__bf16*)(ws + 0 * MB);      // 4 MB  [S*H][64]
    __bf16* k_bf   = (__bf16*)(ws + 4 * MB);      // 4 MB  [S*H][64]
    __bf16* vt     = (__bf16*)(ws + 8 * MB);      // 4 MB  [H][64][S]
    __bf16* ao     = (__bf16*)(ws + 12 * MB);     // 4 MB  [S][512]
    __bf16* wfc_bf = (__bf16*)(ws + 16 * MB);     // 0.5 MB
    unsigned int* mpack = (unsigned int*)(ws + 17 * MB);  // 2 MB [S][128]
    const size_t base = 19 * MB;
    int nsplit = 1, split_steps = 128;
    if (ws_size >= base + 3 * (8 * MB) + 3 * 131072)      { nsplit = 3; split_steps = 43; }
    else if (ws_size >= base + 2 * (8 * MB) + 2 * 131072) { nsplit = 2; split_steps = 64; }
    float* opart = (float*)(ws + base);
    float* stats = (float*)(ws + base + (size_t)nsplit * 8 * MB);

    pre_kernel<<<3104, 256, 0, stream>>>(query, key, value, Wq, bq, Wk, bk, Wv, bv,
                                         q_bf, k_bf, vt, mask, mpack, Wfc, wfc_bf);
    if (nsplit > 1) {
        attn_kernel<<<512 * nsplit, 256, 0, stream>>>(q_bf, k_bf, vt, mpack,
                                                      split_steps, opart, stats, ao);
        combine_kernel<<<8192, 256, 0, stream>>>(opart, stats, ao, nsplit);
    } else {
        attn_kernel<<<512, 256, 0, stream>>>(q_bf, k_bf, vt, mpack,
                                             split_steps, nullptr, nullptr, ao);
    }
    fc_kernel<<<512, 256, 0, stream>>>(ao, wfc_bf, bfc, (float*)d_out);
}

// Round 8
// 135.562 us; speedup vs baseline: 1.6365x; 1.0201x over previous
//
#include <hip/hip_runtime.h>
#include <hip/hip_bf16.h>

#define S_LEN 4096
#define DMODEL 512
#define NHEAD 8
#define HDIM 64

typedef __bf16 bf16x8 __attribute__((ext_vector_type(8)));
typedef __bf16 bf16x4 __attribute__((ext_vector_type(4)));
typedef float f32x4 __attribute__((ext_vector_type(4)));

#define S2EXP 0.18033688011112042f   // 0.125 * log2(e), folded into Q projection

__device__ __forceinline__ void gload_lds16(const void* g, void* l) {
    __builtin_amdgcn_global_load_lds((const __attribute__((address_space(1))) void*)g,
                                     (__attribute__((address_space(3))) void*)l, 16, 0, 0);
}

// ---------------- fused prologue ----------------
// bid <  512 : q+k projection (MFMA); q output pre-scaled by S2EXP
// bid < 1024 : v projection (MFMA) + transpose to vt[h][d][s]
// bid < 3072 : mask bit-packing
// bid < 3104 : Wfc f32->bf16
__global__ __launch_bounds__(256) void pre_kernel(const float* __restrict__ xq,
                                                  const float* __restrict__ xk,
                                                  const float* __restrict__ xv,
                                                  const float* __restrict__ Wq,
                                                  const float* __restrict__ bq,
                                                  const float* __restrict__ Wk,
                                                  const float* __restrict__ bk,
                                                  const float* __restrict__ Wv,
                                                  const float* __restrict__ bv,
                                                  __bf16* __restrict__ yq,
                                                  __bf16* __restrict__ yk,
                                                  __bf16* __restrict__ vt,
                                                  const int* __restrict__ mask,
                                                  unsigned int* __restrict__ pack,
                                                  const float* __restrict__ Wfc,
                                                  __bf16* __restrict__ wfc_bf) {
    __shared__ float T[64][65];
    int bid = blockIdx.x;
    int t = threadIdx.x, wave = t >> 6, lane = t & 63, lg = lane >> 4, lc = lane & 15;
    if (bid < 512) {
        int r0 = bid * 64 + wave * 16;
        const float* xrq = xq + (size_t)(r0 + lc) * 64 + lg * 8;
        const float* xrk = xk + (size_t)(r0 + lc) * 64 + lg * 8;
        bf16x8 aq[2], ak[2];
#pragma unroll
        for (int c = 0; c < 2; ++c) {
            f32x4 u0 = *(const f32x4*)(xrq + c * 32);
            f32x4 u1 = *(const f32x4*)(xrq + c * 32 + 4);
            f32x4 v0 = *(const f32x4*)(xrk + c * 32);
            f32x4 v1 = *(const f32x4*)(xrk + c * 32 + 4);
            bf16x8 a, b;
#pragma unroll
            for (int j = 0; j < 4; ++j) {
                a[j] = (__bf16)u0[j]; a[4 + j] = (__bf16)u1[j];
                b[j] = (__bf16)v0[j]; b[4 + j] = (__bf16)v1[j];
            }
            aq[c] = a; ak[c] = b;
        }
#pragma unroll
        for (int nt = 0; nt < 4; ++nt) {
            const float* wq = Wq + (size_t)(nt * 16 + lc) * 64 + lg * 8;
            const float* wk = Wk + (size_t)(nt * 16 + lc) * 64 + lg * 8;
            f32x4 cq = {0, 0, 0, 0}, ck = {0, 0, 0, 0};
#pragma unroll
            for (int c = 0; c < 2; ++c) {
                f32x4 u0 = *(const f32x4*)(wq + c * 32);
                f32x4 u1 = *(const f32x4*)(wq + c * 32 + 4);
                f32x4 v0 = *(const f32x4*)(wk + c * 32);
                f32x4 v1 = *(const f32x4*)(wk + c * 32 + 4);
                bf16x8 bw, bw2;
#pragma unroll
                for (int j = 0; j < 4; ++j) {
                    bw[j] = (__bf16)u0[j]; bw[4 + j] = (__bf16)u1[j];
                    bw2[j] = (__bf16)v0[j]; bw2[4 + j] = (__bf16)v1[j];
                }
                cq = __builtin_amdgcn_mfma_f32_16x16x32_bf16(aq[c], bw, cq, 0, 0, 0);
                ck = __builtin_amdgcn_mfma_f32_16x16x32_bf16(ak[c], bw2, ck, 0, 0, 0);
            }
            float bqv = bq[nt * 16 + lc], bkv = bk[nt * 16 + lc];
#pragma unroll
            for (int r = 0; r < 4; ++r) {
                yq[(size_t)(r0 + lg * 4 + r) * 64 + nt * 16 + lc] = (__bf16)((cq[r] + bqv) * S2EXP);
                yk[(size_t)(r0 + lg * 4 + r) * 64 + nt * 16 + lc] = (__bf16)(ck[r] + bkv);
            }
        }
    } else if (bid < 1024) {
        int vb = bid - 512;
        int h = vb & 7, s0 = (vb >> 3) * 64;
        const float* xr = xv + ((size_t)(s0 + wave * 16 + lc) * 8 + h) * 64 + lg * 8;
        bf16x8 av[2];
#pragma unroll
        for (int c = 0; c < 2; ++c) {
            f32x4 u0 = *(const f32x4*)(xr + c * 32);
            f32x4 u1 = *(const f32x4*)(xr + c * 32 + 4);
            bf16x8 a;
#pragma unroll
            for (int j = 0; j < 4; ++j) { a[j] = (__bf16)u0[j]; a[4 + j] = (__bf16)u1[j]; }
            av[c] = a;
        }
#pragma unroll
        for (int nt = 0; nt < 4; ++nt) {
            const float* wv = Wv + (size_t)(nt * 16 + lc) * 64 + lg * 8;
            f32x4 cv = {0, 0, 0, 0};
#pragma unroll
            for (int c = 0; c < 2; ++c) {
                f32x4 u0 = *(const f32x4*)(wv + c * 32);
                f32x4 u1 = *(const f32x4*)(wv + c * 32 + 4);
                bf16x8 bw;
#pragma unroll
                for (int j = 0; j < 4; ++j) { bw[j] = (__bf16)u0[j]; bw[4 + j] = (__bf16)u1[j]; }
                cv = __builtin_amdgcn_mfma_f32_16x16x32_bf16(av[c], bw, cv, 0, 0, 0);
            }
            float bvv = bv[nt * 16 + lc];
#pragma unroll
            for (int r = 0; r < 4; ++r) T[wave * 16 + lg * 4 + r][nt * 16 + lc] = cv[r] + bvv;
        }
        __syncthreads();
        int d = t >> 2, qr = t & 3;
        bf16x8 w0, w1;
#pragma unroll
        for (int i = 0; i < 8; ++i) {
            w0[i] = (__bf16)T[qr * 16 + i][d];
            w1[i] = (__bf16)T[qr * 16 + 8 + i][d];
        }
        __bf16* dst = vt + ((size_t)h * 64 + d) * 4096 + s0 + qr * 16;
        *(bf16x8*)(dst) = w0;
        *(bf16x8*)(dst + 8) = w1;
    } else if (bid < 3072) {
        int wid = (bid - 1024) * 4 + (t >> 6);
#pragma unroll 4
        for (int it = 0; it < 32; ++it) {
            int gw = wid * 32 + it;
            int qi = gw >> 6, seg = gw & 63;
            unsigned long long bits = __ballot(mask[(size_t)qi * 4096 + seg * 64 + lane] != 0);
            if (lane == 0)
                *(unsigned long long*)(&pack[(size_t)qi * 128 + seg * 2]) = bits;
        }
    } else {
        int b = bid - 3072;
        const f32x4* s4 = (const f32x4*)Wfc;
#pragma unroll
        for (int i = 0; i < 8; ++i) {
            int idx = (b * 8 + i) * 256 + t;
            f32x4 v = s4[idx];
            bf16x4 o;
#pragma unroll
            for (int j = 0; j < 4; ++j) o[j] = (__bf16)v[j];
            *(bf16x4*)(wfc_bf + (size_t)idx * 4) = o;
        }
    }
}

// ---------------- flash attention: KV-step 32, minimized per-element VALU ----------------
// block: h = bid&7 (head -> XCD), qt = (bid>>3)&63, sp = bid>>9
__global__ __launch_bounds__(256, 6) void attn_kernel(const __bf16* __restrict__ qb,
                                                      const __bf16* __restrict__ kb,
                                                      const __bf16* __restrict__ vt,
                                                      const unsigned int* __restrict__ mp,
                                                      int split_steps,
                                                      float* __restrict__ opart,
                                                      float* __restrict__ stats,
                                                      __bf16* __restrict__ ao) {
    int bid = blockIdx.x;
    int h = bid & 7, qt = (bid >> 3) & 63, sp = bid >> 9;
    int kv0 = sp * split_steps * 32;
    int nsteps = min(split_steps, 128 - sp * split_steps);
    int t = threadIdx.x, wave = t >> 6, lane = t & 63, lg = lane >> 4, lc = lane & 15;
    int q0 = qt * 64 + wave * 16;

    __shared__ __bf16 Kt[2][32 * 64];    // 4KB/buf: k-rows, 128B, XOR swz ((row&7)<<4)
    __shared__ __bf16 Vt[2][64 * 32];    // 4KB/buf: d-rows, 64B, chunk-rotation swz
    __shared__ __bf16 P[4][16 * 32];     // 1KB/wave: q-rows, 64B, chunk-rotation swz

    int srK = lane >> 3;
    int cgK = (lane & 7) ^ srK;                      // inverse XOR swizzle (K)
    int srV = lane >> 2;
    int cgV = ((lane & 3) - ((lane >> 3) & 3)) & 3;  // inverse rotation (V)

    const __bf16* qrow = qb + ((size_t)(q0 + lc) * 8 + h) * 64 + lg * 8;
    bf16x8 qf0 = *(const bf16x8*)(qrow);
    bf16x8 qf1 = *(const bf16x8*)(qrow + 32);

    bf16x8 onesf;
#pragma unroll
    for (int j = 0; j < 8; ++j) onesf[j] = (__bf16)1.0f;

    f32x4 o0 = {0,0,0,0}, o1 = {0,0,0,0}, o2 = {0,0,0,0}, o3 = {0,0,0,0};
    f32x4 l_acc = {0,0,0,0};

    const unsigned int* mrow = mp + (size_t)(q0 + lc) * 128;
    const __bf16* vbase = vt + (size_t)h * 64 * 4096;

    // ---- stage tile 0 ----
    gload_lds16(kb + (size_t)(kv0 + wave * 8 + srK) * 512 + h * 64 + cgK * 8, &Kt[0][wave * 512]);
    gload_lds16(vbase + (size_t)(wave * 16 + srV) * 4096 + kv0 + cgV * 8,     &Vt[0][wave * 512]);
    __syncthreads();

    int rotP = (lc >> 1) & 3;
    int lg4 = lg * 4;
    for (int step = 0; step < nsteps; ++step) {
        int cur = step & 1;
        int kb_i = kv0 + step * 32;
        if (step < nsteps - 1) {
            int nxt = kb_i + 32;
            gload_lds16(kb + (size_t)(nxt + wave * 8 + srK) * 512 + h * 64 + cgK * 8, &Kt[cur ^ 1][wave * 512]);
            gload_lds16(vbase + (size_t)(wave * 16 + srV) * 4096 + nxt + cgV * 8,     &Vt[cur ^ 1][wave * 512]);
        }
        // ---- QK^T swapped (Q pre-scaled): sc = score*0.125*log2e ----
        const char* Kb = (const char*)&Kt[cur][0];
        f32x4 sc[2];
#pragma unroll
        for (int kc = 0; kc < 2; ++kc) {
            int row = kc * 16 + lc;
            int sw = (row & 7) << 4;
            bf16x8 kf0 = *(const bf16x8*)(Kb + ((row * 128 + lg * 16) ^ sw));
            bf16x8 kf1 = *(const bf16x8*)(Kb + ((row * 128 + 64 + lg * 16) ^ sw));
            f32x4 z = {0,0,0,0};
            z = __builtin_amdgcn_mfma_f32_16x16x32_bf16(kf0, qf0, z, 0, 0, 0);
            z = __builtin_amdgcn_mfma_f32_16x16x32_bf16(kf1, qf1, z, 0, 0, 0);
            sc[kc] = z;
        }
        // ---- p = exp2(sc), masked to 0 via bfe_i32 sign-extract + AND ----
        unsigned int mws = mrow[kb_i >> 5] >> lg4;   // hoisted per-lane shift
        char* pbase = (char*)&P[wave][0];
#pragma unroll
        for (int kc = 0; kc < 2; ++kc) {
            bf16x4 pk;
#pragma unroll
            for (int r = 0; r < 4; ++r) {
                float p = __builtin_amdgcn_exp2f(sc[kc][r]);
                int sel = __builtin_amdgcn_sbfe((int)mws, kc * 16 + r, 1);  // 0 or 0xFFFFFFFF
                pk[r] = (__bf16)__int_as_float(__float_as_int(p) & sel);
            }
            int phys = ((kc * 2 + (lg >> 1)) + rotP) & 3;
            int byte = lc * 64 + phys * 16 + (lg & 1) * 8;
            *(bf16x4*)(pbase + byte) = pk;
        }
        // ---- PV (+ l row-sum via ones-B MFMA): single K=32 chunk ----
        const char* Vb = (const char*)&Vt[cur][0];
        bf16x8 pf = *(const bf16x8*)(pbase + (lc * 64 + (((lg + rotP) & 3) * 16)));
        l_acc = __builtin_amdgcn_mfma_f32_16x16x32_bf16(pf, onesf, l_acc, 0, 0, 0);
#pragma unroll
        for (int dt = 0; dt < 4; ++dt) {
            int row = dt * 16 + lc;
            bf16x8 vf = *(const bf16x8*)(Vb + (row * 64 + (((lg + rotP) & 3) * 16)));
            if (dt == 0) o0 = __builtin_amdgcn_mfma_f32_16x16x32_bf16(pf, vf, o0, 0, 0, 0);
            if (dt == 1) o1 = __builtin_amdgcn_mfma_f32_16x16x32_bf16(pf, vf, o1, 0, 0, 0);
            if (dt == 2) o2 = __builtin_amdgcn_mfma_f32_16x16x32_bf16(pf, vf, o2, 0, 0, 0);
            if (dt == 3) o3 = __builtin_amdgcn_mfma_f32_16x16x32_bf16(pf, vf, o3, 0, 0, 0);
        }
        __syncthreads();
    }
    if (opart) {
        if (lc == 0) {
#pragma unroll
            for (int r = 0; r < 4; ++r)
                stats[(size_t)sp * 32768 + (size_t)(q0 + lg * 4 + r) * 8 + h] = l_acc[r];
        }
#pragma unroll
        for (int r = 0; r < 4; ++r) {
            size_t rh = (size_t)sp * 32768 + (size_t)(q0 + lg * 4 + r) * 8 + h;
            float* dst = opart + rh * 64;
            dst[0 * 16 + lc] = o0[r];
            dst[1 * 16 + lc] = o1[r];
            dst[2 * 16 + lc] = o2[r];
            dst[3 * 16 + lc] = o3[r];
        }
    } else {
#pragma unroll
        for (int r = 0; r < 4; ++r) {
            float inv = 1.0f / l_acc[r];
            int row = q0 + lg * 4 + r;
            __bf16* dst = ao + (size_t)row * 512 + h * 64;
            dst[0 * 16 + lc] = (__bf16)(o0[r] * inv);
            dst[1 * 16 + lc] = (__bf16)(o1[r] * inv);
            dst[2 * 16 + lc] = (__bf16)(o2[r] * inv);
            dst[3 * 16 + lc] = (__bf16)(o3[r] * inv);
        }
    }
}

// ---------------- split-KV combine (no-max softmax: plain sums) ----------------
__global__ __launch_bounds__(256) void combine_kernel(const float* __restrict__ opart,
                                                      const float* __restrict__ stats,
                                                      __bf16* __restrict__ ao, int nsplit) {
    int t = threadIdx.x, lane = t & 63, w = t >> 6;
    int rh = blockIdx.x * 4 + w;     // row*8 + h
    float L = 0.f, acc = 0.f;
#pragma unroll 4
    for (int sp = 0; sp < nsplit; ++sp) {
        L += stats[(size_t)sp * 32768 + rh];
        acc += opart[((size_t)sp * 32768 + rh) * 64 + lane];
    }
    int row = rh >> 3, h = rh & 7;
    ao[(size_t)row * 512 + h * 64 + lane] = (__bf16)(acc / L);
}

// ---------------- final FC: out[s][n] = sum_k ao[s][k] * Wfc[n][k] + bfc[n] ----------------
__global__ __launch_bounds__(256) void fc_kernel(const __bf16* __restrict__ ao,
                                                 const __bf16* __restrict__ Wb,
                                                 const float* __restrict__ bfc,
                                                 float* __restrict__ out) {
    int bid = blockIdx.x;
    int stile = bid >> 3, nt = bid & 7;
    int t = threadIdx.x, wave = t >> 6, lane = t & 63, lg = lane >> 4, lc = lane & 15;
    int s0 = stile * 64 + wave * 16;
    int n0 = nt * 64;
    f32x4 c0 = {0,0,0,0}, c1 = {0,0,0,0}, c2 = {0,0,0,0}, c3 = {0,0,0,0};
    for (int k0 = 0; k0 < 512; k0 += 32) {
        bf16x8 af = *(const bf16x8*)(ao + (size_t)(s0 + lc) * 512 + k0 + lg * 8);
        const __bf16* wb = Wb + k0 + lg * 8;
        c0 = __builtin_amdgcn_mfma_f32_16x16x32_bf16(af, *(const bf16x8*)(wb + (size_t)(n0 + 0 * 16 + lc) * 512), c0, 0, 0, 0);
        c1 = __builtin_amdgcn_mfma_f32_16x16x32_bf16(af, *(const bf16x8*)(wb + (size_t)(n0 + 1 * 16 + lc) * 512), c1, 0, 0, 0);
        c2 = __builtin_amdgcn_mfma_f32_16x16x32_bf16(af, *(const bf16x8*)(wb + (size_t)(n0 + 2 * 16 + lc) * 512), c2, 0, 0, 0);
        c3 = __builtin_amdgcn_mfma_f32_16x16x32_bf16(af, *(const bf16x8*)(wb + (size_t)(n0 + 3 * 16 + lc) * 512), c3, 0, 0, 0);
    }
#pragma unroll
    for (int r = 0; r < 4; ++r) {
        int row = s0 + lg * 4 + r;
        float* dst = out + (size_t)row * 512 + n0;
        dst[0 * 16 + lc] = c0[r] + bfc[n0 + 0 * 16 + lc];
        dst[1 * 16 + lc] = c1[r] + bfc[n0 + 1 * 16 + lc];
        dst[2 * 16 + lc] = c2[r] + bfc[n0 + 2 * 16 + lc];
        dst[3 * 16 + lc] = c3[r] + bfc[n0 + 3 * 16 + lc];
    }
}

extern "C" void kernel_launch(void* const* d_in, const int* in_sizes, int n_in,
                              void* d_out, int out_size, void* d_ws, size_t ws_size,
                              hipStream_t stream) {
    const float* query = (const float*)d_in[0];
    const float* key   = (const float*)d_in[1];
    const float* value = (const float*)d_in[2];
    const int*   mask  = (const int*)d_in[3];
    const float* Wq  = (const float*)d_in[4];
    const float* bq  = (const float*)d_in[5];
    const float* Wk  = (const float*)d_in[6];
    const float* bk  = (const float*)d_in[7];
    const float* Wv  = (const float*)d_in[8];
    const float* bv  = (const float*)d_in[9];
    const float* Wfc = (const float*)d_in[10];
    const float* bfc = (const float*)d_in[11];

    char* ws = (char*)d_ws;
    const size_t MB = 1024 * 1024;
    __bf16* q_bf   = (__bf16*)(ws + 0 * MB);      // 4 MB  [S*H][64]
    __bf16* k_bf   = (__bf16*)(ws + 4 * MB);      // 4 MB  [S*H][64]
    __bf16* vt     = (__bf16*)(ws + 8 * MB);      // 4 MB  [H][64][S]
    __bf16* ao     = (__bf16*)(ws + 12 * MB);     // 4 MB  [S][512]
    __bf16* wfc_bf = (__bf16*)(ws + 16 * MB);     // 0.5 MB
    unsigned int* mpack = (unsigned int*)(ws + 17 * MB);  // 2 MB [S][128]
    const size_t base = 19 * MB;
    int nsplit = 1, split_steps = 128;
    if (ws_size >= base + 3 * (8 * MB) + 3 * 131072)      { nsplit = 3; split_steps = 43; }
    else if (ws_size >= base + 2 * (8 * MB) + 2 * 131072) { nsplit = 2; split_steps = 64; }
    float* opart = (float*)(ws + base);
    float* stats = (float*)(ws + base + (size_t)nsplit * 8 * MB);

    pre_kernel<<<3104, 256, 0, stream>>>(query, key, value, Wq, bq, Wk, bk, Wv, bv,
                                         q_bf, k_bf, vt, mask, mpack, Wfc, wfc_bf);
    if (nsplit > 1) {
        attn_kernel<<<512 * nsplit, 256, 0, stream>>>(q_bf, k_bf, vt, mpack,
                                                      split_steps, opart, stats, ao);
        combine_kernel<<<8192, 256, 0, stream>>>(opart, stats, ao, nsplit);
    } else {
        attn_kernel<<<512, 256, 0, stream>>>(q_bf, k_bf, vt, mpack,
                                             split_steps, nullptr, nullptr, ao);
    }
    fc_kernel<<<512, 256, 0, stream>>>(ao, wfc_bf, bfc, (float*)d_out);
}